// Round 8
// baseline (752.132 us; speedup 1.0000x reference)
//
#include <hip/hip_runtime.h>
#include <math.h>

typedef unsigned short ushort;
typedef __attribute__((ext_vector_type(8))) short short8;
typedef __attribute__((ext_vector_type(8))) unsigned short ushort8;
typedef __attribute__((ext_vector_type(4))) float f32x4;
typedef unsigned int u32;

#define VM_WAIT(N) asm volatile("s_waitcnt vmcnt(" #N ")" ::: "memory")
#define SBAR() asm volatile("s_barrier" ::: "memory")

// 2-bit slot swizzle for 64B rows: spreads 16-row column slices over all
// 8 bank-quads (2 accesses/quad per 16 lanes -> conflict-free throughput).
__device__ __forceinline__ int swz4(int row) {
  return (row & 3) ^ ((row >> 2) & 3);
}

__device__ __forceinline__ ushort f2bf(float f) {
  u32 u = __float_as_uint(f);
  return (ushort)((u + 0x7FFF + ((u >> 16) & 1)) >> 16);
}
__device__ __forceinline__ float bf2f(ushort u) {
  u32 v = ((u32)u) << 16;
  return __uint_as_float(v);
}

__device__ __forceinline__ void gload16(const void* g, void* l) {
  __builtin_amdgcn_global_load_lds(
      (const __attribute__((address_space(1))) u32*)g,
      (__attribute__((address_space(3))) u32*)l, 16, 0, 0);
}

// ---------------- fp32 VALU GEMM (static Wf GEMMs only), z=which -------------
#define BKK 32
#define LDSP 68
__global__ __launch_bounds__(256) void gemm_generic(
    const float* __restrict__ A, const float* __restrict__ Bm, const float* __restrict__ Bm2,
    float* __restrict__ C, float* __restrict__ C2,
    int M, int N, int K, long sAi, long sAk, long sBj, long sBk, long sCi)
{
  __shared__ __align__(16) float lds_a[BKK * LDSP];
  __shared__ __align__(16) float lds_b[BKK * LDSP];
  const float* Bb = blockIdx.z ? Bm2 : Bm;
  float* Cc = blockIdx.z ? C2 : C;
  const int i0 = blockIdx.y * 64;
  const int j0 = blockIdx.x * 64;
  const int tid = threadIdx.x;
  const int tx = tid & 15, ty = tid >> 4;
  float acc[4][4] = {};
  for (int k0 = 0; k0 < K; k0 += BKK) {
    for (int idx = tid; idx < BKK * 64; idx += 256) {
      int kk = idx & (BKK - 1), ii = idx >> 5;
      int gi = i0 + ii, gk = k0 + kk;
      lds_a[kk * LDSP + ii] = (gi < M && gk < K) ? A[(long)gi * sAi + (long)gk * sAk] : 0.f;
    }
    for (int idx = tid; idx < BKK * 64; idx += 256) {
      int kk = idx & (BKK - 1), jj = idx >> 5;
      int gj = j0 + jj, gk = k0 + kk;
      lds_b[kk * LDSP + jj] = (gj < N && gk < K) ? Bb[(long)gj * sBj + (long)gk * sBk] : 0.f;
    }
    __syncthreads();
    #pragma unroll
    for (int kk = 0; kk < BKK; ++kk) {
      const float4 a4 = *reinterpret_cast<const float4*>(&lds_a[kk * LDSP + ty * 4]);
      const float4 b4 = *reinterpret_cast<const float4*>(&lds_b[kk * LDSP + tx * 4]);
      const float av[4] = {a4.x, a4.y, a4.z, a4.w};
      const float bv[4] = {b4.x, b4.y, b4.z, b4.w};
      #pragma unroll
      for (int a = 0; a < 4; ++a)
        #pragma unroll
        for (int b = 0; b < 4; ++b)
          acc[a][b] = fmaf(av[a], bv[b], acc[a][b]);
    }
    __syncthreads();
  }
  for (int a = 0; a < 4; ++a) {
    int gi = i0 + ty * 4 + a;
    if (gi >= M) continue;
    for (int b = 0; b < 4; ++b) {
      int gj = j0 + tx * 4 + b;
      if (gj >= N) continue;
      Cc[(long)gi * sCi + gj] = acc[a][b];
    }
  }
}

// ---------------- merged k GEMM: 128x128 tile, single-buffered, z=which ------
__global__ __launch_bounds__(256) void mfma_gemm(
    const ushort* __restrict__ A0, const ushort* __restrict__ A1,
    const ushort* __restrict__ B0, const ushort* __restrict__ B1,
    const float* __restrict__ bias0, const float* __restrict__ bias1,
    float* __restrict__ C0, float* __restrict__ C1,
    int M, int N, int K, long sAi, long sBj, long sCi)
{
  __shared__ ushort As[128 * 64];
  __shared__ ushort Bs[128 * 64];
  const int which = blockIdx.z;
  const ushort* Ab = which ? A1 : A0;
  const ushort* Bb = which ? B1 : B0;
  const float* bias = which ? bias1 : bias0;
  float* C = which ? C1 : C0;
  const int i0 = blockIdx.y * 128;
  const int j0 = blockIdx.x * 128;
  const int tid = threadIdx.x;
  const int wave = tid >> 6, lane = tid & 63;
  const int wm = wave >> 1, wn = wave & 1;
  const int col16 = lane & 15, krow = lane >> 4;

  f32x4 acc[4][4] = {};

  for (int k0 = 0; k0 < K; k0 += 64) {
    #pragma unroll
    for (int it = 0; it < 4; ++it) {
      int chunk = it * 256 + wave * 64 + lane;
      int row = chunk >> 3, s = chunk & 7;
      int kc = s ^ (row & 7);
      int gi = i0 + row; if (gi >= M) gi = M - 1;
      gload16(Ab + (long)gi * sAi + k0 + kc * 8, &As[chunk * 8]);
    }
    #pragma unroll
    for (int it = 0; it < 4; ++it) {
      int chunk = it * 256 + wave * 64 + lane;
      int row = chunk >> 3, s = chunk & 7;
      int kc = s ^ (row & 7);
      int gj = j0 + row; if (gj >= N) gj = N - 1;
      gload16(Bb + (long)gj * sBj + k0 + kc * 8, &Bs[chunk * 8]);
    }
    __syncthreads();
    #pragma unroll
    for (int ks = 0; ks < 2; ++ks) {
      short8 af[4], bfr[4];
      #pragma unroll
      for (int mi = 0; mi < 4; ++mi) {
        int row = wm * 64 + mi * 16 + col16;
        int slot = (ks * 4 + krow) ^ (row & 7);
        af[mi] = *(const short8*)&As[row * 64 + slot * 8];
      }
      #pragma unroll
      for (int nj = 0; nj < 4; ++nj) {
        int row = wn * 64 + nj * 16 + col16;
        int slot = (ks * 4 + krow) ^ (row & 7);
        bfr[nj] = *(const short8*)&Bs[row * 64 + slot * 8];
      }
      #pragma unroll
      for (int mi = 0; mi < 4; ++mi)
        #pragma unroll
        for (int nj = 0; nj < 4; ++nj)
          acc[mi][nj] = __builtin_amdgcn_mfma_f32_16x16x32_bf16(
              af[mi], bfr[nj], acc[mi][nj], 0, 0, 0);
    }
    __syncthreads();
  }

  const int r0 = krow * 4;
  #pragma unroll
  for (int mi = 0; mi < 4; ++mi) {
    int gi0 = i0 + wm * 64 + mi * 16 + r0;
    #pragma unroll
    for (int nj = 0; nj < 4; ++nj) {
      int gj = j0 + wn * 64 + nj * 16 + col16;
      f32x4 a = acc[mi][nj];
      #pragma unroll
      for (int r = 0; r < 4; ++r) {
        int gi = gi0 + r;
        if (gi >= M || gj >= N) continue;
        C[(long)gi * sCi + gj] = a[r] + bias[gj];
      }
    }
  }
}

// ---------------- fused att-logit GEMM + column softmax, counted vmcnt -------
// z = (which, bz): grid (4, Bc, 2)
__global__ __launch_bounds__(256) void att_gemm(
    const ushort* __restrict__ Wl0, const ushort* __restrict__ Wl1,
    const ushort* __restrict__ E0, const ushort* __restrict__ E1,
    const float* __restrict__ bl0, const float* __restrict__ bl1,
    ushort* __restrict__ a0, ushort* __restrict__ a1out)
{
  __shared__ ushort Aws[2][208 * 32];
  __shared__ ushort Bws[2][64 * 32];
  __shared__ float blds[208];
  const int which = blockIdx.z;
  const int bz = blockIdx.y;
  const ushort* Wl = which ? Wl1 : Wl0;
  const ushort* Bb = (which ? E1 : E0) + 50432L * bz;
  const float* bl = which ? bl1 : bl0;
  ushort* aout = which ? a1out : a0;
  const int l0 = blockIdx.x * 64;
  const int tid = threadIdx.x, wave = tid >> 6, lane = tid & 63;
  const int col16 = lane & 15, kq = lane >> 4;

  if (tid < 208) blds[tid] = (tid < 197) ? bl[tid] : 0.f;

  f32x4 acc[13] = {};

  auto stage = [&](int buf, int k0) {
    const int lrow = lane >> 2, s = lane & 3;
    #pragma unroll
    for (int c0 = 0; c0 < 5; ++c0) {
      int c = wave + c0 * 4;
      if (c >= 17) break;                         // wave-uniform
      if (c < 13) {
        int row = c * 16 + lrow;
        int gr = row < 197 ? row : 196;
        int kc = s ^ swz4(row);
        gload16(Wl + (long)gr * 256 + k0 + kc * 8,
                (char*)(&Aws[buf][0]) + c * 1024 + lane * 16);
      } else {
        int row = (c - 13) * 16 + lrow;
        int gl = l0 + row; if (gl > 196) gl = 196;
        int kc = s ^ swz4(row);
        gload16(Bb + (long)gl * 256 + k0 + kc * 8,
                (char*)(&Bws[buf][0]) + (c - 13) * 1024 + lane * 16);
      }
    }
  };

  stage(0, 0);
  for (int t = 0; t < 7; ++t) {
    int cur = t & 1;
    if (t + 1 < 7) {
      stage(cur ^ 1, (t + 1) * 32);
      if (wave == 0) VM_WAIT(5); else VM_WAIT(4);   // own next-stage in-flight
    } else {
      VM_WAIT(0);
    }
    SBAR();
    int brow = wave * 16 + col16;
    short8 bf = *(const short8*)((const char*)(&Bws[cur][0]) +
                                 brow * 64 + ((kq ^ swz4(brow)) << 4));
    #pragma unroll
    for (int j = 0; j < 13; ++j) {
      int arow = j * 16 + col16;
      short8 af = *(const short8*)((const char*)(&Aws[cur][0]) +
                                   arow * 64 + ((kq ^ swz4(arow)) << 4));
      acc[j] = __builtin_amdgcn_mfma_f32_16x16x32_bf16(af, bf, acc[j], 0, 0, 0);
    }
    SBAR();
  }

  const int c = l0 + wave * 16 + col16;
  float mx = -INFINITY;
  #pragma unroll
  for (int j = 0; j < 13; ++j)
    #pragma unroll
    for (int r = 0; r < 4; ++r) {
      int m = j * 16 + kq * 4 + r;
      float v = acc[j][r] + blds[m];
      v = (m < 197) ? v : -INFINITY;
      acc[j][r] = v;
      mx = fmaxf(mx, v);
    }
  mx = fmaxf(mx, __shfl_xor(mx, 16));
  mx = fmaxf(mx, __shfl_xor(mx, 32));
  float s = 0.f;
  #pragma unroll
  for (int j = 0; j < 13; ++j)
    #pragma unroll
    for (int r = 0; r < 4; ++r) {
      int m = j * 16 + kq * 4 + r;
      float e = (m < 197) ? __expf(acc[j][r] - mx) : 0.f;
      acc[j][r] = e;
      s += e;
    }
  s += __shfl_xor(s, 16);
  s += __shfl_xor(s, 32);
  const float inv = 1.f / s;
  ushort* ab = aout + 50432L * bz;
  #pragma unroll
  for (int j = 0; j < 13; ++j)
    #pragma unroll
    for (int r = 0; r < 4; ++r) {
      int m = j * 16 + kq * 4 + r;
      if (m < 197)
        ab[(long)m * 256 + c] = (c < 197) ? f2bf(acc[j][r] * inv) : (ushort)0;
    }
}

// ---------------- merged v/out GEMM: 128x224 tile, counted-vmcnt 2-phase -----
// 1D grid = 2 * mtiles * batches; which = upper/lower half.
// mode 1: bf16 out + bias[row], cols [N,224)->0
// mode 3: f32 out, gamma[0]*acc + bf2f(resid[ci])
__global__ __launch_bounds__(256) void vout_gemm(
    const ushort* __restrict__ A0, const ushort* __restrict__ A1,
    const ushort* __restrict__ B0, const ushort* __restrict__ B1,
    const float* __restrict__ bias0, const float* __restrict__ bias1,
    const ushort* __restrict__ resid0, const ushort* __restrict__ resid1,
    const float* __restrict__ g0, const float* __restrict__ g1,
    void* __restrict__ C0, void* __restrict__ C1,
    int N, int K, long sAi, long bAs, long sBj, long bBs,
    long sCi, long bCs, int mtiles, int batches, int mode)
{
  __shared__ ushort As[2][128 * 32];   // 8 KB / buf
  __shared__ ushort Bs[2][224 * 32];   // 14 KB / buf
  const int per = mtiles * batches;
  int bid = blockIdx.x;
  const int which = bid / per;
  bid -= which * per;
  const ushort* A = which ? A1 : A0;
  const ushort* Bm = which ? B1 : B0;
  const float* bias = which ? bias1 : bias0;
  const ushort* resid = which ? resid1 : resid0;
  const float* gammaPtr = which ? g1 : g0;
  void* C = which ? C1 : C0;

  int mtile, bz;
  if ((batches & 7) == 0) {
    int xcd = bid & 7, sid = bid >> 3;
    mtile = sid % mtiles;
    bz = (sid / mtiles) * 8 + xcd;
  } else {
    mtile = bid % mtiles;
    bz = bid / mtiles;
  }
  const ushort* Ab = A + bAs * bz + (long)(mtile * 128) * sAi;
  const ushort* Bb = Bm + bBs * bz;
  const int tid = threadIdx.x, wave = tid >> 6, lane = tid & 63;
  const int wr = wave >> 1, wc = wave & 1;
  const int col16 = lane & 15, kq = lane >> 4;

  f32x4 acc[4][7] = {};

  // 22 chunks of 1 KB: A rows 0..127 (8), B rows 0..223 (14).
  // wave w stages chunks {w, w+4, ...}: waves 0,1 -> 6 chunks; waves 2,3 -> 5.
  auto stage = [&](int buf, int k0) {
    const int lrow = lane >> 2, s = lane & 3;
    #pragma unroll
    for (int c0 = 0; c0 < 6; ++c0) {
      int c = wave + c0 * 4;
      if (c >= 22) break;                         // wave-uniform
      if (c < 8) {
        int row = c * 16 + lrow;
        int kc = s ^ swz4(row);
        gload16(Ab + (long)row * sAi + k0 + kc * 8,
                (char*)(&As[buf][0]) + c * 1024 + lane * 16);
      } else {
        int row = (c - 8) * 16 + lrow;
        int gj = row < N ? row : N - 1;
        int kc = s ^ swz4(row);
        gload16(Bb + (long)gj * sBj + k0 + kc * 8,
                (char*)(&Bs[buf][0]) + (c - 8) * 1024 + lane * 16);
      }
    }
  };

  const int nt = K >> 5;
  stage(0, 0);
  for (int t = 0; t < nt; ++t) {
    int cur = t & 1;
    if (t + 1 < nt) {
      stage(cur ^ 1, (t + 1) << 5);
      if (wave < 2) VM_WAIT(6); else VM_WAIT(5);   // own next-stage in-flight
    } else {
      VM_WAIT(0);
    }
    SBAR();                                        // t-data visible to all
    short8 af[4];
    #pragma unroll
    for (int mi = 0; mi < 4; ++mi) {
      int arow = wr * 64 + mi * 16 + col16;
      af[mi] = *(const short8*)((const char*)(&As[cur][0]) +
                                arow * 64 + ((kq ^ swz4(arow)) << 4));
    }
    #pragma unroll
    for (int nj = 0; nj < 7; ++nj) {
      int brow = wc * 112 + nj * 16 + col16;
      short8 bf = *(const short8*)((const char*)(&Bs[cur][0]) +
                                   brow * 64 + ((kq ^ swz4(brow)) << 4));
      #pragma unroll
      for (int mi = 0; mi < 4; ++mi)
        acc[mi][nj] = __builtin_amdgcn_mfma_f32_16x16x32_bf16(
            af[mi], bf, acc[mi][nj], 0, 0, 0);
    }
    SBAR();                                        // reads done; next stage may overwrite
  }

  if (mode == 3) {
    const float g = gammaPtr[0];
    #pragma unroll
    for (int mi = 0; mi < 4; ++mi)
      #pragma unroll
      for (int nj = 0; nj < 7; ++nj) {
        int gj = wc * 112 + nj * 16 + col16;
        if (gj >= N) continue;
        #pragma unroll
        for (int r = 0; r < 4; ++r) {
          int gi = mtile * 128 + wr * 64 + mi * 16 + kq * 4 + r;
          long ci = bCs * bz + (long)gi * sCi + gj;
          ((float*)C)[ci] = g * acc[mi][nj][r] + bf2f(resid[ci]);
        }
      }
  } else {
    #pragma unroll
    for (int mi = 0; mi < 4; ++mi)
      #pragma unroll
      for (int r = 0; r < 4; ++r) {
        int gi = mtile * 128 + wr * 64 + mi * 16 + kq * 4 + r;
        long base = bCs * bz + (long)gi * sCi;
        #pragma unroll
        for (int nj = 0; nj < 7; ++nj) {
          int gj = wc * 112 + nj * 16 + col16;
          ((ushort*)C)[base + gj] = (gj < N) ? f2bf(acc[mi][nj][r] + bias[gi])
                                             : (ushort)0;
        }
      }
  }
}

// ---------------- energy GEMM (fp32 VALU) with fused dual bf16 write ---------
__global__ __launch_bounds__(256) void energy_dual(
    const float* __restrict__ k1, const float* __restrict__ k2,
    ushort* __restrict__ Eb, ushort* __restrict__ ETb)
{
  __shared__ __align__(16) float lds[2][BKK * LDSP];
  const int bz = blockIdx.z;
  const float* Ab = k1 + 18912L * bz;
  const float* Bb = k2 + 18912L * bz;
  const int i0 = blockIdx.y * 64;
  const int j0 = blockIdx.x * 64;
  const int tid = threadIdx.x;
  const int tx = tid & 15, ty = tid >> 4;
  float acc[4][4] = {};
  for (int k0 = 0; k0 < 96; k0 += BKK) {
    for (int idx = tid; idx < BKK * 64; idx += 256) {
      int ii = idx & 63, kk = idx >> 6;
      int gi = i0 + ii, gk = k0 + kk;
      lds[0][kk * LDSP + ii] = (gi < 197 && gk < 96) ? Ab[(long)gk * 197 + gi] : 0.f;
    }
    for (int idx = tid; idx < BKK * 64; idx += 256) {
      int jj = idx & 63, kk = idx >> 6;
      int gj = j0 + jj, gk = k0 + kk;
      lds[1][kk * LDSP + jj] = (gj < 197 && gk < 96) ? Bb[(long)gk * 197 + gj] : 0.f;
    }
    __syncthreads();
    #pragma unroll
    for (int kk = 0; kk < BKK; ++kk) {
      const float4 a4 = *reinterpret_cast<const float4*>(&lds[0][kk * LDSP + ty * 4]);
      const float4 b4 = *reinterpret_cast<const float4*>(&lds[1][kk * LDSP + tx * 4]);
      const float av[4] = {a4.x, a4.y, a4.z, a4.w};
      const float bv[4] = {b4.x, b4.y, b4.z, b4.w};
      #pragma unroll
      for (int a = 0; a < 4; ++a)
        #pragma unroll
        for (int b = 0; b < 4; ++b)
          acc[a][b] = fmaf(av[a], bv[b], acc[a][b]);
    }
    __syncthreads();
  }
  float* trans = &lds[0][0];
  #pragma unroll
  for (int a = 0; a < 4; ++a)
    #pragma unroll
    for (int b = 0; b < 4; ++b)
      trans[(ty * 4 + a) * 68 + tx * 4 + b] = acc[a][b];
  __syncthreads();
  #pragma unroll
  for (int a2 = 0; a2 < 4; ++a2) {
    int lrow = ty * 4 + a2;
    int gl = i0 + lrow;
    if (gl < 197) {
      #pragma unroll
      for (int b2 = 0; b2 < 4; ++b2) {
        int gm = j0 + tx + 16 * b2;
        float v = trans[lrow * 68 + tx + 16 * b2];
        Eb[bz * 50432L + (long)gl * 256 + gm] = (gm < 197) ? f2bf(v) : (ushort)0;
      }
    }
  }
  #pragma unroll
  for (int a2 = 0; a2 < 4; ++a2) {
    int mrow = ty * 4 + a2;
    int gm = j0 + mrow;
    if (gm < 197) {
      #pragma unroll
      for (int b2 = 0; b2 < 4; ++b2) {
        int gl = i0 + tx + 16 * b2;
        float v = trans[(tx + 16 * b2) * 68 + mrow];
        ETb[bz * 50432L + (long)gm * 256 + gl] = (gl < 197) ? f2bf(v) : (ushort)0;
      }
    }
  }
}

// ---------------- merged small helpers ---------------------------------------
__global__ void fuse_bias2(const float* __restrict__ Wks,
                           const float* __restrict__ bk1, const float* __restrict__ bk2,
                           const float* __restrict__ bks,
                           float* __restrict__ bf1, float* __restrict__ bf2) {
  int c = threadIdx.x;
  if (c >= 192) return;
  const float* bk = (c < 96) ? bk1 : bk2;
  float* bf = (c < 96) ? bf1 : bf2;
  int cc = (c < 96) ? c : c - 96;
  float s = bks[cc];
  for (int e = 0; e < 96; ++e) s += Wks[cc * 96 + e] * bk[e];
  bf[cc] = s;
}

// all weight conversions in one grid-stride kernel
__global__ __launch_bounds__(256) void conv_weights(
    const float* __restrict__ Wf1, const float* __restrict__ Wf2,
    const float* __restrict__ Wv1, const float* __restrict__ Wv2,
    const float* __restrict__ Wl1, const float* __restrict__ Wl2,
    ushort* __restrict__ Wf1b, ushort* __restrict__ Wf2b,
    ushort* __restrict__ Wv1b, ushort* __restrict__ Wv2b,
    ushort* __restrict__ Wl1b, ushort* __restrict__ Wl2b)
{
  const long total = 147456 + 1179648 + 100864;
  long stride = (long)gridDim.x * blockDim.x;
  for (long i = (long)blockIdx.x * blockDim.x + threadIdx.x; i < total; i += stride) {
    if (i < 147456) {
      long j = i;
      if (j < 73728) Wf1b[j] = f2bf(Wf1[j]);
      else Wf2b[j - 73728] = f2bf(Wf2[j - 73728]);
    } else if (i < 147456 + 1179648) {
      long j = i - 147456;
      if (j < 589824) Wv1b[j] = f2bf(Wv1[j]);
      else Wv2b[j - 589824] = f2bf(Wv2[j - 589824]);
    } else {
      long j = i - 147456 - 1179648;
      int w2 = j >= 50432;
      if (w2) j -= 50432;
      int r = (int)(j >> 8), cc = (int)(j & 255);
      const float* s = w2 ? Wl2 : Wl1;
      ushort* d = w2 ? Wl2b : Wl1b;
      d[j] = (cc < 197) ? f2bf(s[(long)r * 197 + cc]) : (ushort)0;
    }
  }
}

__global__ __launch_bounds__(256) void conv_xy(const float* __restrict__ x,
                                               const float* __restrict__ y,
                                               ushort* __restrict__ xb,
                                               ushort* __restrict__ yb, long n8) {
  long i = (long)blockIdx.x * blockDim.x + threadIdx.x;
  long stride = (long)gridDim.x * blockDim.x;
  for (; i < 2 * n8; i += stride) {
    const float* s = (i < n8) ? x : y;
    ushort* d = (i < n8) ? xb : yb;
    long j = (i < n8) ? i : i - n8;
    float4 a = ((const float4*)s)[2 * j];
    float4 b = ((const float4*)s)[2 * j + 1];
    ushort8 o;
    o[0] = f2bf(a.x); o[1] = f2bf(a.y); o[2] = f2bf(a.z); o[3] = f2bf(a.w);
    o[4] = f2bf(b.x); o[5] = f2bf(b.y); o[6] = f2bf(b.z); o[7] = f2bf(b.w);
    *(ushort8*)&d[j * 8] = o;
  }
}

// ---------------- launcher ---------------------------------------------------
extern "C" void kernel_launch(void* const* d_in, const int* in_sizes, int n_in,
                              void* d_out, int out_size, void* d_ws, size_t ws_size,
                              hipStream_t stream) {
  const float* x   = (const float*)d_in[0];
  const float* y   = (const float*)d_in[1];
  const float* Wk1 = (const float*)d_in[2];
  const float* bk1 = (const float*)d_in[3];
  const float* Wk2 = (const float*)d_in[4];
  const float* bk2 = (const float*)d_in[5];
  const float* Wks = (const float*)d_in[6];
  const float* bks = (const float*)d_in[7];
  const float* Wl1 = (const float*)d_in[8];
  const float* bl1 = (const float*)d_in[9];
  const float* Wl2 = (const float*)d_in[10];
  const float* bl2 = (const float*)d_in[11];
  const float* Wv1 = (const float*)d_in[12];
  const float* bv1 = (const float*)d_in[13];
  const float* Wv2 = (const float*)d_in[14];
  const float* bv2 = (const float*)d_in[15];
  const float* gamma1 = (const float*)d_in[16];
  const float* gamma2 = (const float*)d_in[17];
  float* out = (float*)d_out;

  const int B = 256, L = 197, D = 768;
  const long LD  = (long)L * D;    // 151296
  const long LDK = (long)L * 96;   // 18912

  const size_t staticBytes = 3446784;
  // xb yb k1 k2 Eb ETb a1 a2 vT vT2
  const size_t perB = 605184 + 151296 + 201728 + 201728 + 786432; // 1946368
  int Bc = 256;
  while (Bc > 8 && staticBytes + (size_t)Bc * perB > ws_size) Bc >>= 1;

  char* p = (char*)d_ws;
  auto carve = [&](size_t bytes) { char* r = p; p += bytes; return r; };
  float*  Wf1   = (float*)carve(73728 * 4);
  float*  Wf2   = (float*)carve(73728 * 4);
  float*  bf1   = (float*)carve(512);
  float*  bf2   = (float*)carve(512);
  ushort* Wv1b  = (ushort*)carve(589824 * 2);
  ushort* Wv2b  = (ushort*)carve(589824 * 2);
  ushort* Wf1b  = (ushort*)carve(73728 * 2);
  ushort* Wf2b  = (ushort*)carve(73728 * 2);
  ushort* Wl1b  = (ushort*)carve(50432 * 2);
  ushort* Wl2b  = (ushort*)carve(50432 * 2);
  ushort* xb    = (ushort*)carve((size_t)Bc * LD * 2);
  ushort* yb    = (ushort*)carve((size_t)Bc * LD * 2);
  float*  k1    = (float*)carve((size_t)Bc * LDK * 4);
  float*  k2    = (float*)carve((size_t)Bc * LDK * 4);
  ushort* Eb    = (ushort*)carve((size_t)Bc * 50432 * 2);
  ushort* ETbuf = (ushort*)carve((size_t)Bc * 50432 * 2);
  ushort* a1    = (ushort*)carve((size_t)Bc * 50432 * 2);
  ushort* a2    = (ushort*)carve((size_t)Bc * 50432 * 2);
  ushort* vT    = (ushort*)carve((size_t)Bc * 196608 * 2);
  ushort* vT2   = (ushort*)carve((size_t)Bc * 196608 * 2);

  dim3 blk(256);

  // ---- static weight prep (3 launches) ----
  gemm_generic<<<dim3(12, 2, 2), blk, 0, stream>>>(Wks, Wk1, Wk2, Wf1, Wf2,
      96, 768, 96, 96, 1, 1, 768, 768);
  fuse_bias2<<<1, 192, 0, stream>>>(Wks, bk1, bk2, bks, bf1, bf2);
  conv_weights<<<dim3(1024), blk, 0, stream>>>(Wf1, Wf2, Wv1, Wv2, Wl1, Wl2,
      Wf1b, Wf2b, Wv1b, Wv2b, Wl1b, Wl2b);

  for (int c0 = 0; c0 < B; c0 += Bc) {
    const float* xc = x + (long)c0 * LD;
    const float* yc = y + (long)c0 * LD;
    const int Mr = Bc * L;
    const int gym = (Mr + 127) / 128;

    conv_xy<<<dim3(2048), blk, 0, stream>>>(xc, yc, xb, yb, (long)Bc * LD / 8);

    // k1 = xb @ Wf1b^T + bf1 ; k2 = yb @ Wf2b^T + bf2  (merged, z=2)
    mfma_gemm<<<dim3(1, gym, 2), blk, 0, stream>>>(xb, yb, Wf1b, Wf2b, bf1, bf2,
        k1, k2, Mr, 96, 768, 768, 768, 96);

    // energy + dual bf16 transpose write
    energy_dual<<<dim3(4, 4, Bc), blk, 0, stream>>>(k1, k2, Eb, ETbuf);

    // fused att logits + softmax (merged pair)
    att_gemm<<<dim3(4, Bc, 2), blk, 0, stream>>>(Wl1b, Wl2b, Eb, ETbuf,
        bl1, bl2, a1, a2);

    // v pair: vT = (Wv2 . y^T), vT2 = (Wv1 . x^T); bf16, cols [197,224)=0
    vout_gemm<<<dim3(12 * Bc), blk, 0, stream>>>(Wv2b, Wv1b, yb, xb, bv2, bv1,
        nullptr, nullptr, nullptr, nullptr, vT, vT2,
        197, 768, 768, 0, 768, LD, 256, 196608, 6, Bc, 1);

    // out pair: out_x = g1*vT.a1^T + x ; out_y = g2*vT2.a2^T + y  (resid bf16)
    vout_gemm<<<dim3(12 * Bc), blk, 0, stream>>>(vT, vT2, a1, a2, nullptr, nullptr,
        xb, yb, gamma1, gamma2,
        out + (long)c0 * LD, out + (long)B * LD + (long)c0 * LD,
        197, 224, 256, 196608, 256, 50432, 197, LD, 6, Bc, 3);
  }
}

// Round 9
// 703.760 us; speedup vs baseline: 1.0687x; 1.0687x over previous
//
#include <hip/hip_runtime.h>
#include <math.h>

typedef unsigned short ushort;
typedef __attribute__((ext_vector_type(8))) short short8;
typedef __attribute__((ext_vector_type(8))) unsigned short ushort8;
typedef __attribute__((ext_vector_type(4))) float f32x4;
typedef unsigned int u32;

#define VM_WAIT(N) asm volatile("s_waitcnt vmcnt(" #N ")" ::: "memory")
#define SBAR() asm volatile("s_barrier" ::: "memory")

__device__ __forceinline__ int swz4(int row) {
  return (row & 3) ^ ((row >> 2) & 3);
}

__device__ __forceinline__ ushort f2bf(float f) {
  u32 u = __float_as_uint(f);
  return (ushort)((u + 0x7FFF + ((u >> 16) & 1)) >> 16);
}
__device__ __forceinline__ float bf2f(ushort u) {
  u32 v = ((u32)u) << 16;
  return __uint_as_float(v);
}

__device__ __forceinline__ void gload16(const void* g, void* l) {
  __builtin_amdgcn_global_load_lds(
      (const __attribute__((address_space(1))) u32*)g,
      (__attribute__((address_space(3))) u32*)l, 16, 0, 0);
}

// ---------------- fp32 VALU GEMM (static Wf GEMMs only), z=which -------------
#define BKK 32
#define LDSP 68
__global__ __launch_bounds__(256) void gemm_generic(
    const float* __restrict__ A, const float* __restrict__ Bm, const float* __restrict__ Bm2,
    float* __restrict__ C, float* __restrict__ C2,
    int M, int N, int K, long sAi, long sAk, long sBj, long sBk, long sCi)
{
  __shared__ __align__(16) float lds_a[BKK * LDSP];
  __shared__ __align__(16) float lds_b[BKK * LDSP];
  const float* Bb = blockIdx.z ? Bm2 : Bm;
  float* Cc = blockIdx.z ? C2 : C;
  const int i0 = blockIdx.y * 64;
  const int j0 = blockIdx.x * 64;
  const int tid = threadIdx.x;
  const int tx = tid & 15, ty = tid >> 4;
  float acc[4][4] = {};
  for (int k0 = 0; k0 < K; k0 += BKK) {
    for (int idx = tid; idx < BKK * 64; idx += 256) {
      int kk = idx & (BKK - 1), ii = idx >> 5;
      int gi = i0 + ii, gk = k0 + kk;
      lds_a[kk * LDSP + ii] = (gi < M && gk < K) ? A[(long)gi * sAi + (long)gk * sAk] : 0.f;
    }
    for (int idx = tid; idx < BKK * 64; idx += 256) {
      int kk = idx & (BKK - 1), jj = idx >> 5;
      int gj = j0 + jj, gk = k0 + kk;
      lds_b[kk * LDSP + jj] = (gj < N && gk < K) ? Bb[(long)gj * sBj + (long)gk * sBk] : 0.f;
    }
    __syncthreads();
    #pragma unroll
    for (int kk = 0; kk < BKK; ++kk) {
      const float4 a4 = *reinterpret_cast<const float4*>(&lds_a[kk * LDSP + ty * 4]);
      const float4 b4 = *reinterpret_cast<const float4*>(&lds_b[kk * LDSP + tx * 4]);
      const float av[4] = {a4.x, a4.y, a4.z, a4.w};
      const float bv[4] = {b4.x, b4.y, b4.z, b4.w};
      #pragma unroll
      for (int a = 0; a < 4; ++a)
        #pragma unroll
        for (int b = 0; b < 4; ++b)
          acc[a][b] = fmaf(av[a], bv[b], acc[a][b]);
    }
    __syncthreads();
  }
  for (int a = 0; a < 4; ++a) {
    int gi = i0 + ty * 4 + a;
    if (gi >= M) continue;
    for (int b = 0; b < 4; ++b) {
      int gj = j0 + tx * 4 + b;
      if (gj >= N) continue;
      Cc[(long)gi * sCi + gj] = acc[a][b];
    }
  }
}

// ---------------- merged k GEMM: 128x128 tile, single-buffered, z=which ------
__global__ __launch_bounds__(256) void mfma_gemm(
    const ushort* __restrict__ A0, const ushort* __restrict__ A1,
    const ushort* __restrict__ B0, const ushort* __restrict__ B1,
    const float* __restrict__ bias0, const float* __restrict__ bias1,
    float* __restrict__ C0, float* __restrict__ C1,
    int M, int N, int K, long sAi, long sBj, long sCi)
{
  __shared__ ushort As[128 * 64];
  __shared__ ushort Bs[128 * 64];
  const int which = blockIdx.z;
  const ushort* Ab = which ? A1 : A0;
  const ushort* Bb = which ? B1 : B0;
  const float* bias = which ? bias1 : bias0;
  float* C = which ? C1 : C0;
  const int i0 = blockIdx.y * 128;
  const int j0 = blockIdx.x * 128;
  const int tid = threadIdx.x;
  const int wave = tid >> 6, lane = tid & 63;
  const int wm = wave >> 1, wn = wave & 1;
  const int col16 = lane & 15, krow = lane >> 4;

  f32x4 acc[4][4] = {};

  for (int k0 = 0; k0 < K; k0 += 64) {
    #pragma unroll
    for (int it = 0; it < 4; ++it) {
      int chunk = it * 256 + wave * 64 + lane;
      int row = chunk >> 3, s = chunk & 7;
      int kc = s ^ (row & 7);
      int gi = i0 + row; if (gi >= M) gi = M - 1;
      gload16(Ab + (long)gi * sAi + k0 + kc * 8, &As[chunk * 8]);
    }
    #pragma unroll
    for (int it = 0; it < 4; ++it) {
      int chunk = it * 256 + wave * 64 + lane;
      int row = chunk >> 3, s = chunk & 7;
      int kc = s ^ (row & 7);
      int gj = j0 + row; if (gj >= N) gj = N - 1;
      gload16(Bb + (long)gj * sBj + k0 + kc * 8, &Bs[chunk * 8]);
    }
    __syncthreads();
    #pragma unroll
    for (int ks = 0; ks < 2; ++ks) {
      short8 af[4], bfr[4];
      #pragma unroll
      for (int mi = 0; mi < 4; ++mi) {
        int row = wm * 64 + mi * 16 + col16;
        int slot = (ks * 4 + krow) ^ (row & 7);
        af[mi] = *(const short8*)&As[row * 64 + slot * 8];
      }
      #pragma unroll
      for (int nj = 0; nj < 4; ++nj) {
        int row = wn * 64 + nj * 16 + col16;
        int slot = (ks * 4 + krow) ^ (row & 7);
        bfr[nj] = *(const short8*)&Bs[row * 64 + slot * 8];
      }
      #pragma unroll
      for (int mi = 0; mi < 4; ++mi)
        #pragma unroll
        for (int nj = 0; nj < 4; ++nj)
          acc[mi][nj] = __builtin_amdgcn_mfma_f32_16x16x32_bf16(
              af[mi], bfr[nj], acc[mi][nj], 0, 0, 0);
    }
    __syncthreads();
  }

  const int r0 = krow * 4;
  #pragma unroll
  for (int mi = 0; mi < 4; ++mi) {
    int gi0 = i0 + wm * 64 + mi * 16 + r0;
    #pragma unroll
    for (int nj = 0; nj < 4; ++nj) {
      int gj = j0 + wn * 64 + nj * 16 + col16;
      f32x4 a = acc[mi][nj];
      #pragma unroll
      for (int r = 0; r < 4; ++r) {
        int gi = gi0 + r;
        if (gi >= M || gj >= N) continue;
        C[(long)gi * sCi + gj] = a[r] + bias[gj];
      }
    }
  }
}

// ---------------- flat v GEMM: M=768 x N=Bc*224 x K=768, BK=32, 2-phase ------
// C[which][d][n] = sum_e Wv[d][e] * src[b*197 + l][e] + bv[d], n = b*224+l,
// cols l in [197,224) -> 0.  32 KB LDS (dbuf) -> 4-5 blocks/CU.
__global__ __launch_bounds__(256) void vbig_gemm(
    const ushort* __restrict__ A0, const ushort* __restrict__ A1,
    const ushort* __restrict__ B0, const ushort* __restrict__ B1,
    const float* __restrict__ bias0, const float* __restrict__ bias1,
    ushort* __restrict__ C0, ushort* __restrict__ C1,
    int ntiles, long Nc)
{
  __shared__ ushort As[2][128 * 32];   // 8 KB each
  __shared__ ushort Bs[2][128 * 32];
  const int per = 6 * ntiles;
  int bid = blockIdx.x;
  const int which = bid / per;
  bid -= which * per;
  const int ntile = bid % ntiles;      // stride-ntiles siblings share B panel (same XCD)
  const int mtile = bid / ntiles;
  const ushort* Ab = (which ? A1 : A0) + (long)(mtile * 128) * 768;
  const ushort* Bb = which ? B1 : B0;
  const float* bias = which ? bias1 : bias0;
  ushort* C = which ? C1 : C0;
  const int n0 = ntile * 128;
  const int tid = threadIdx.x, wave = tid >> 6, lane = tid & 63;
  const int wm = wave >> 1, wn = wave & 1;
  const int col16 = lane & 15, kq = lane >> 4;

  f32x4 acc[4][4] = {};

  // 16 chunks of 1 KB (A rows 0..127 -> 8, B cols 0..127 -> 8); 4 per wave.
  auto stage = [&](int buf, int k0) {
    const int lrow = lane >> 2, s = lane & 3;
    #pragma unroll
    for (int c0 = 0; c0 < 4; ++c0) {
      int c = wave * 4 + c0;
      if (c < 8) {
        int row = c * 16 + lrow;
        int kc = s ^ swz4(row);
        gload16(Ab + (long)row * 768 + k0 + kc * 8,
                (char*)(&As[buf][0]) + c * 1024 + lane * 16);
      } else {
        int j = (c - 8) * 16 + lrow;
        int n = n0 + j;
        int b = n / 224;
        int l = n - b * 224;
        int grow = b * 197 + (l < 197 ? l : 196);
        int kc = s ^ swz4(j);
        gload16(Bb + (long)grow * 768 + k0 + kc * 8,
                (char*)(&Bs[buf][0]) + (c - 8) * 1024 + lane * 16);
      }
    }
  };

  stage(0, 0);
  for (int t = 0; t < 24; ++t) {
    int cur = t & 1;
    if (t + 1 < 24) {
      stage(cur ^ 1, (t + 1) << 5);
      VM_WAIT(4);                 // own 4 next-stage loads in flight; stage t done
    } else {
      VM_WAIT(0);
    }
    SBAR();
    short8 af[4], bfr[4];
    #pragma unroll
    for (int mi = 0; mi < 4; ++mi) {
      int arow = wm * 64 + mi * 16 + col16;
      af[mi] = *(const short8*)((const char*)(&As[cur][0]) +
                                arow * 64 + ((kq ^ swz4(arow)) << 4));
    }
    #pragma unroll
    for (int nj = 0; nj < 4; ++nj) {
      int brow = wn * 64 + nj * 16 + col16;
      bfr[nj] = *(const short8*)((const char*)(&Bs[cur][0]) +
                                 brow * 64 + ((kq ^ swz4(brow)) << 4));
    }
    #pragma unroll
    for (int mi = 0; mi < 4; ++mi)
      #pragma unroll
      for (int nj = 0; nj < 4; ++nj)
        acc[mi][nj] = __builtin_amdgcn_mfma_f32_16x16x32_bf16(
            af[mi], bfr[nj], acc[mi][nj], 0, 0, 0);
    SBAR();
  }

  #pragma unroll
  for (int mi = 0; mi < 4; ++mi) {
    #pragma unroll
    for (int r = 0; r < 4; ++r) {
      int gi = mtile * 128 + wm * 64 + mi * 16 + kq * 4 + r;
      float bv = bias[gi];
      long base = (long)gi * Nc;
      #pragma unroll
      for (int nj = 0; nj < 4; ++nj) {
        int n = n0 + wn * 64 + nj * 16 + col16;
        int b = n / 224;
        int l = n - b * 224;
        C[base + n] = (l < 197) ? f2bf(acc[mi][nj][r] + bv) : (ushort)0;
      }
    }
  }
}

// ---------------- fused att-logit GEMM + column softmax, counted vmcnt -------
__global__ __launch_bounds__(256) void att_gemm(
    const ushort* __restrict__ Wl0, const ushort* __restrict__ Wl1,
    const ushort* __restrict__ E0, const ushort* __restrict__ E1,
    const float* __restrict__ bl0, const float* __restrict__ bl1,
    ushort* __restrict__ a0, ushort* __restrict__ a1out)
{
  __shared__ ushort Aws[2][208 * 32];
  __shared__ ushort Bws[2][64 * 32];
  __shared__ float blds[208];
  const int which = blockIdx.z;
  const int bz = blockIdx.y;
  const ushort* Wl = which ? Wl1 : Wl0;
  const ushort* Bb = (which ? E1 : E0) + 50432L * bz;
  const float* bl = which ? bl1 : bl0;
  ushort* aout = which ? a1out : a0;
  const int l0 = blockIdx.x * 64;
  const int tid = threadIdx.x, wave = tid >> 6, lane = tid & 63;
  const int col16 = lane & 15, kq = lane >> 4;

  if (tid < 208) blds[tid] = (tid < 197) ? bl[tid] : 0.f;

  f32x4 acc[13] = {};

  auto stage = [&](int buf, int k0) {
    const int lrow = lane >> 2, s = lane & 3;
    #pragma unroll
    for (int c0 = 0; c0 < 5; ++c0) {
      int c = wave + c0 * 4;
      if (c >= 17) break;                         // wave-uniform
      if (c < 13) {
        int row = c * 16 + lrow;
        int gr = row < 197 ? row : 196;
        int kc = s ^ swz4(row);
        gload16(Wl + (long)gr * 256 + k0 + kc * 8,
                (char*)(&Aws[buf][0]) + c * 1024 + lane * 16);
      } else {
        int row = (c - 13) * 16 + lrow;
        int gl = l0 + row; if (gl > 196) gl = 196;
        int kc = s ^ swz4(row);
        gload16(Bb + (long)gl * 256 + k0 + kc * 8,
                (char*)(&Bws[buf][0]) + (c - 13) * 1024 + lane * 16);
      }
    }
  };

  stage(0, 0);
  for (int t = 0; t < 7; ++t) {
    int cur = t & 1;
    if (t + 1 < 7) {
      stage(cur ^ 1, (t + 1) * 32);
      if (wave == 0) VM_WAIT(5); else VM_WAIT(4);
    } else {
      VM_WAIT(0);
    }
    SBAR();
    int brow = wave * 16 + col16;
    short8 bf = *(const short8*)((const char*)(&Bws[cur][0]) +
                                 brow * 64 + ((kq ^ swz4(brow)) << 4));
    #pragma unroll
    for (int j = 0; j < 13; ++j) {
      int arow = j * 16 + col16;
      short8 af = *(const short8*)((const char*)(&Aws[cur][0]) +
                                   arow * 64 + ((kq ^ swz4(arow)) << 4));
      acc[j] = __builtin_amdgcn_mfma_f32_16x16x32_bf16(af, bf, acc[j], 0, 0, 0);
    }
    SBAR();
  }

  const int c = l0 + wave * 16 + col16;
  float mx = -INFINITY;
  #pragma unroll
  for (int j = 0; j < 13; ++j)
    #pragma unroll
    for (int r = 0; r < 4; ++r) {
      int m = j * 16 + kq * 4 + r;
      float v = acc[j][r] + blds[m];
      v = (m < 197) ? v : -INFINITY;
      acc[j][r] = v;
      mx = fmaxf(mx, v);
    }
  mx = fmaxf(mx, __shfl_xor(mx, 16));
  mx = fmaxf(mx, __shfl_xor(mx, 32));
  float s = 0.f;
  #pragma unroll
  for (int j = 0; j < 13; ++j)
    #pragma unroll
    for (int r = 0; r < 4; ++r) {
      int m = j * 16 + kq * 4 + r;
      float e = (m < 197) ? __expf(acc[j][r] - mx) : 0.f;
      acc[j][r] = e;
      s += e;
    }
  s += __shfl_xor(s, 16);
  s += __shfl_xor(s, 32);
  const float inv = 1.f / s;
  ushort* ab = aout + 50432L * bz;
  #pragma unroll
  for (int j = 0; j < 13; ++j)
    #pragma unroll
    for (int r = 0; r < 4; ++r) {
      int m = j * 16 + kq * 4 + r;
      if (m < 197)
        ab[(long)m * 256 + c] = (c < 197) ? f2bf(acc[j][r] * inv) : (ushort)0;
    }
}

// ---------------- out GEMM: 128x224 full-N tile, counted-vmcnt 2-phase -------
// f32 out, gamma[0]*acc + bf2f(resid[ci]).  A = vTall (row stride sAi, batch
// offset bAs), B = att (per-batch), K=224.
__global__ __launch_bounds__(256) void vout_gemm(
    const ushort* __restrict__ A0, const ushort* __restrict__ A1,
    const ushort* __restrict__ B0, const ushort* __restrict__ B1,
    const ushort* __restrict__ resid0, const ushort* __restrict__ resid1,
    const float* __restrict__ g0, const float* __restrict__ g1,
    float* __restrict__ C0, float* __restrict__ C1,
    int N, int K, long sAi, long bAs, long sBj, long bBs,
    long sCi, long bCs, int mtiles, int batches)
{
  __shared__ ushort As[2][128 * 32];   // 8 KB / buf
  __shared__ ushort Bs[2][224 * 32];   // 14 KB / buf
  const int per = mtiles * batches;
  int bid = blockIdx.x;
  const int which = bid / per;
  bid -= which * per;
  const ushort* A = which ? A1 : A0;
  const ushort* Bm = which ? B1 : B0;
  const ushort* resid = which ? resid1 : resid0;
  const float* gammaPtr = which ? g1 : g0;
  float* C = which ? C1 : C0;

  int mtile, bz;
  if ((batches & 7) == 0) {
    int xcd = bid & 7, sid = bid >> 3;
    mtile = sid % mtiles;
    bz = (sid / mtiles) * 8 + xcd;
  } else {
    mtile = bid % mtiles;
    bz = bid / mtiles;
  }
  const ushort* Ab = A + bAs * bz + (long)(mtile * 128) * sAi;
  const ushort* Bb = Bm + bBs * bz;
  const int tid = threadIdx.x, wave = tid >> 6, lane = tid & 63;
  const int wr = wave >> 1, wc = wave & 1;
  const int col16 = lane & 15, kq = lane >> 4;

  f32x4 acc[4][7] = {};

  auto stage = [&](int buf, int k0) {
    const int lrow = lane >> 2, s = lane & 3;
    #pragma unroll
    for (int c0 = 0; c0 < 6; ++c0) {
      int c = wave + c0 * 4;
      if (c >= 22) break;                         // wave-uniform
      if (c < 8) {
        int row = c * 16 + lrow;
        int kc = s ^ swz4(row);
        gload16(Ab + (long)row * sAi + k0 + kc * 8,
                (char*)(&As[buf][0]) + c * 1024 + lane * 16);
      } else {
        int row = (c - 8) * 16 + lrow;
        int gj = row < N ? row : N - 1;
        int kc = s ^ swz4(row);
        gload16(Bb + (long)gj * sBj + k0 + kc * 8,
                (char*)(&Bs[buf][0]) + (c - 8) * 1024 + lane * 16);
      }
    }
  };

  const int nt = K >> 5;
  stage(0, 0);
  for (int t = 0; t < nt; ++t) {
    int cur = t & 1;
    if (t + 1 < nt) {
      stage(cur ^ 1, (t + 1) << 5);
      if (wave < 2) VM_WAIT(6); else VM_WAIT(5);
    } else {
      VM_WAIT(0);
    }
    SBAR();
    short8 af[4];
    #pragma unroll
    for (int mi = 0; mi < 4; ++mi) {
      int arow = wr * 64 + mi * 16 + col16;
      af[mi] = *(const short8*)((const char*)(&As[cur][0]) +
                                arow * 64 + ((kq ^ swz4(arow)) << 4));
    }
    #pragma unroll
    for (int nj = 0; nj < 7; ++nj) {
      int brow = wc * 112 + nj * 16 + col16;
      short8 bf = *(const short8*)((const char*)(&Bs[cur][0]) +
                                   brow * 64 + ((kq ^ swz4(brow)) << 4));
      #pragma unroll
      for (int mi = 0; mi < 4; ++mi)
        acc[mi][nj] = __builtin_amdgcn_mfma_f32_16x16x32_bf16(
            af[mi], bf, acc[mi][nj], 0, 0, 0);
    }
    SBAR();
  }

  const float g = gammaPtr[0];
  #pragma unroll
  for (int mi = 0; mi < 4; ++mi)
    #pragma unroll
    for (int nj = 0; nj < 7; ++nj) {
      int gj = wc * 112 + nj * 16 + col16;
      if (gj >= N) continue;
      #pragma unroll
      for (int r = 0; r < 4; ++r) {
        int gi = mtile * 128 + wr * 64 + mi * 16 + kq * 4 + r;
        long ci = bCs * bz + (long)gi * sCi + gj;
        C[ci] = g * acc[mi][nj][r] + bf2f(resid[ci]);
      }
    }
}

// ---------------- energy GEMM (fp32 VALU) with fused dual bf16 write ---------
__global__ __launch_bounds__(256) void energy_dual(
    const float* __restrict__ k1, const float* __restrict__ k2,
    ushort* __restrict__ Eb, ushort* __restrict__ ETb)
{
  __shared__ __align__(16) float lds[2][BKK * LDSP];
  const int bz = blockIdx.z;
  const float* Ab = k1 + 18912L * bz;
  const float* Bb = k2 + 18912L * bz;
  const int i0 = blockIdx.y * 64;
  const int j0 = blockIdx.x * 64;
  const int tid = threadIdx.x;
  const int tx = tid & 15, ty = tid >> 4;
  float acc[4][4] = {};
  for (int k0 = 0; k0 < 96; k0 += BKK) {
    for (int idx = tid; idx < BKK * 64; idx += 256) {
      int ii = idx & 63, kk = idx >> 6;
      int gi = i0 + ii, gk = k0 + kk;
      lds[0][kk * LDSP + ii] = (gi < 197 && gk < 96) ? Ab[(long)gk * 197 + gi] : 0.f;
    }
    for (int idx = tid; idx < BKK * 64; idx += 256) {
      int jj = idx & 63, kk = idx >> 6;
      int gj = j0 + jj, gk = k0 + kk;
      lds[1][kk * LDSP + jj] = (gj < 197 && gk < 96) ? Bb[(long)gk * 197 + gj] : 0.f;
    }
    __syncthreads();
    #pragma unroll
    for (int kk = 0; kk < BKK; ++kk) {
      const float4 a4 = *reinterpret_cast<const float4*>(&lds[0][kk * LDSP + ty * 4]);
      const float4 b4 = *reinterpret_cast<const float4*>(&lds[1][kk * LDSP + tx * 4]);
      const float av[4] = {a4.x, a4.y, a4.z, a4.w};
      const float bv[4] = {b4.x, b4.y, b4.z, b4.w};
      #pragma unroll
      for (int a = 0; a < 4; ++a)
        #pragma unroll
        for (int b = 0; b < 4; ++b)
          acc[a][b] = fmaf(av[a], bv[b], acc[a][b]);
    }
    __syncthreads();
  }
  float* trans = &lds[0][0];
  #pragma unroll
  for (int a = 0; a < 4; ++a)
    #pragma unroll
    for (int b = 0; b < 4; ++b)
      trans[(ty * 4 + a) * 68 + tx * 4 + b] = acc[a][b];
  __syncthreads();
  #pragma unroll
  for (int a2 = 0; a2 < 4; ++a2) {
    int lrow = ty * 4 + a2;
    int gl = i0 + lrow;
    if (gl < 197) {
      #pragma unroll
      for (int b2 = 0; b2 < 4; ++b2) {
        int gm = j0 + tx + 16 * b2;
        float v = trans[lrow * 68 + tx + 16 * b2];
        Eb[bz * 50432L + (long)gl * 256 + gm] = (gm < 197) ? f2bf(v) : (ushort)0;
      }
    }
  }
  #pragma unroll
  for (int a2 = 0; a2 < 4; ++a2) {
    int mrow = ty * 4 + a2;
    int gm = j0 + mrow;
    if (gm < 197) {
      #pragma unroll
      for (int b2 = 0; b2 < 4; ++b2) {
        int gl = i0 + tx + 16 * b2;
        float v = trans[(tx + 16 * b2) * 68 + mrow];
        ETb[bz * 50432L + (long)gm * 256 + gl] = (gl < 197) ? f2bf(v) : (ushort)0;
      }
    }
  }
}

// ---------------- merged small helpers ---------------------------------------
__global__ void fuse_bias2(const float* __restrict__ Wks,
                           const float* __restrict__ bk1, const float* __restrict__ bk2,
                           const float* __restrict__ bks,
                           float* __restrict__ bf1, float* __restrict__ bf2) {
  int c = threadIdx.x;
  if (c >= 192) return;
  const float* bk = (c < 96) ? bk1 : bk2;
  float* bf = (c < 96) ? bf1 : bf2;
  int cc = (c < 96) ? c : c - 96;
  float s = bks[cc];
  for (int e = 0; e < 96; ++e) s += Wks[cc * 96 + e] * bk[e];
  bf[cc] = s;
}

__global__ __launch_bounds__(256) void conv_weights(
    const float* __restrict__ Wf1, const float* __restrict__ Wf2,
    const float* __restrict__ Wv1, const float* __restrict__ Wv2,
    const float* __restrict__ Wl1, const float* __restrict__ Wl2,
    ushort* __restrict__ Wf1b, ushort* __restrict__ Wf2b,
    ushort* __restrict__ Wv1b, ushort* __restrict__ Wv2b,
    ushort* __restrict__ Wl1b, ushort* __restrict__ Wl2b)
{
  const long total = 147456 + 1179648 + 100864;
  long stride = (long)gridDim.x * blockDim.x;
  for (long i = (long)blockIdx.x * blockDim.x + threadIdx.x; i < total; i += stride) {
    if (i < 147456) {
      long j = i;
      if (j < 73728) Wf1b[j] = f2bf(Wf1[j]);
      else Wf2b[j - 73728] = f2bf(Wf2[j - 73728]);
    } else if (i < 147456 + 1179648) {
      long j = i - 147456;
      if (j < 589824) Wv1b[j] = f2bf(Wv1[j]);
      else Wv2b[j - 589824] = f2bf(Wv2[j - 589824]);
    } else {
      long j = i - 147456 - 1179648;
      int w2 = j >= 50432;
      if (w2) j -= 50432;
      int r = (int)(j >> 8), cc = (int)(j & 255);
      const float* s = w2 ? Wl2 : Wl1;
      ushort* d = w2 ? Wl2b : Wl1b;
      d[j] = (cc < 197) ? f2bf(s[(long)r * 197 + cc]) : (ushort)0;
    }
  }
}

__global__ __launch_bounds__(256) void conv_xy(const float* __restrict__ x,
                                               const float* __restrict__ y,
                                               ushort* __restrict__ xb,
                                               ushort* __restrict__ yb, long n8) {
  long i = (long)blockIdx.x * blockDim.x + threadIdx.x;
  long stride = (long)gridDim.x * blockDim.x;
  for (; i < 2 * n8; i += stride) {
    const float* s = (i < n8) ? x : y;
    ushort* d = (i < n8) ? xb : yb;
    long j = (i < n8) ? i : i - n8;
    float4 a = ((const float4*)s)[2 * j];
    float4 b = ((const float4*)s)[2 * j + 1];
    ushort8 o;
    o[0] = f2bf(a.x); o[1] = f2bf(a.y); o[2] = f2bf(a.z); o[3] = f2bf(a.w);
    o[4] = f2bf(b.x); o[5] = f2bf(b.y); o[6] = f2bf(b.z); o[7] = f2bf(b.w);
    *(ushort8*)&d[j * 8] = o;
  }
}

// ---------------- launcher ---------------------------------------------------
extern "C" void kernel_launch(void* const* d_in, const int* in_sizes, int n_in,
                              void* d_out, int out_size, void* d_ws, size_t ws_size,
                              hipStream_t stream) {
  const float* x   = (const float*)d_in[0];
  const float* y   = (const float*)d_in[1];
  const float* Wk1 = (const float*)d_in[2];
  const float* bk1 = (const float*)d_in[3];
  const float* Wk2 = (const float*)d_in[4];
  const float* bk2 = (const float*)d_in[5];
  const float* Wks = (const float*)d_in[6];
  const float* bks = (const float*)d_in[7];
  const float* Wl1 = (const float*)d_in[8];
  const float* bl1 = (const float*)d_in[9];
  const float* Wl2 = (const float*)d_in[10];
  const float* bl2 = (const float*)d_in[11];
  const float* Wv1 = (const float*)d_in[12];
  const float* bv1 = (const float*)d_in[13];
  const float* Wv2 = (const float*)d_in[14];
  const float* bv2 = (const float*)d_in[15];
  const float* gamma1 = (const float*)d_in[16];
  const float* gamma2 = (const float*)d_in[17];
  float* out = (float*)d_out;

  const int B = 256, L = 197, D = 768;
  const long LD  = (long)L * D;    // 151296
  const long LDK = (long)L * 96;   // 18912

  const size_t staticBytes = 3446784;
  // xb yb k1 k2 Eb ETb a1 a2 vTall(x2): per-batch vTall = 224*768*2*2 = 688128
  const size_t perB = 605184 + 151296 + 201728 + 201728 + 688128; // 1848064
  int Bc = 256;
  while (Bc > 8 && staticBytes + (size_t)Bc * perB > ws_size) Bc >>= 1;

  char* p = (char*)d_ws;
  auto carve = [&](size_t bytes) { char* r = p; p += bytes; return r; };
  float*  Wf1   = (float*)carve(73728 * 4);
  float*  Wf2   = (float*)carve(73728 * 4);
  float*  bf1   = (float*)carve(512);
  float*  bf2   = (float*)carve(512);
  ushort* Wv1b  = (ushort*)carve(589824 * 2);
  ushort* Wv2b  = (ushort*)carve(589824 * 2);
  ushort* Wf1b  = (ushort*)carve(73728 * 2);
  ushort* Wf2b  = (ushort*)carve(73728 * 2);
  ushort* Wl1b  = (ushort*)carve(50432 * 2);
  ushort* Wl2b  = (ushort*)carve(50432 * 2);
  ushort* xb    = (ushort*)carve((size_t)Bc * LD * 2);
  ushort* yb    = (ushort*)carve((size_t)Bc * LD * 2);
  float*  k1    = (float*)carve((size_t)Bc * LDK * 4);
  float*  k2    = (float*)carve((size_t)Bc * LDK * 4);
  ushort* Eb    = (ushort*)carve((size_t)Bc * 50432 * 2);
  ushort* ETbuf = (ushort*)carve((size_t)Bc * 50432 * 2);
  ushort* a1    = (ushort*)carve((size_t)Bc * 50432 * 2);
  ushort* a2    = (ushort*)carve((size_t)Bc * 50432 * 2);
  const long Nc = (long)Bc * 224;
  ushort* vT    = (ushort*)carve((size_t)768 * Nc * 2);
  ushort* vT2   = (ushort*)carve((size_t)768 * Nc * 2);

  dim3 blk(256);

  // ---- static weight prep (3 launches) ----
  gemm_generic<<<dim3(12, 2, 2), blk, 0, stream>>>(Wks, Wk1, Wk2, Wf1, Wf2,
      96, 768, 96, 96, 1, 1, 768, 768);
  fuse_bias2<<<1, 192, 0, stream>>>(Wks, bk1, bk2, bks, bf1, bf2);
  conv_weights<<<dim3(1024), blk, 0, stream>>>(Wf1, Wf2, Wv1, Wv2, Wl1, Wl2,
      Wf1b, Wf2b, Wv1b, Wv2b, Wl1b, Wl2b);

  for (int c0 = 0; c0 < B; c0 += Bc) {
    const float* xc = x + (long)c0 * LD;
    const float* yc = y + (long)c0 * LD;
    const int Mr = Bc * L;
    const int gym = (Mr + 127) / 128;

    conv_xy<<<dim3(2048), blk, 0, stream>>>(xc, yc, xb, yb, (long)Bc * LD / 8);

    // k1 = xb @ Wf1b^T + bf1 ; k2 = yb @ Wf2b^T + bf2  (merged, z=2)
    mfma_gemm<<<dim3(1, gym, 2), blk, 0, stream>>>(xb, yb, Wf1b, Wf2b, bf1, bf2,
        k1, k2, Mr, 96, 768, 768, 768, 96);

    // energy + dual bf16 transpose write
    energy_dual<<<dim3(4, 4, Bc), blk, 0, stream>>>(k1, k2, Eb, ETbuf);

    // fused att logits + softmax (merged pair)
    att_gemm<<<dim3(4, Bc, 2), blk, 0, stream>>>(Wl1b, Wl2b, Eb, ETbuf,
        bl1, bl2, a1, a2);

    // flat v pair: vT[d][b*224+l] = Wv2.y^T + bv2 ; vT2 = Wv1.x^T + bv1
    {
      int ntiles = (int)(Nc / 128);
      vbig_gemm<<<dim3(2 * 6 * ntiles), blk, 0, stream>>>(
          Wv2b, Wv1b, yb, xb, bv2, bv1, vT, vT2, ntiles, Nc);
    }

    // out pair: out_x = g1*vT.a1^T + x ; out_y = g2*vT2.a2^T + y  (resid bf16)
    vout_gemm<<<dim3(12 * Bc), blk, 0, stream>>>(vT, vT2, a1, a2,
        xb, yb, gamma1, gamma2,
        out + (long)c0 * LD, out + (long)B * LD + (long)c0 * LD,
        197, 224, Nc, 224, 256, 50432, 197, LD, 6, Bc);
  }
}